// Round 1
// baseline (444.450 us; speedup 1.0000x reference)
//
#include <hip/hip_runtime.h>

// FactorizedSpectralConv2d: B=16, CIN=COUT=64, H=W=128, MH=MW=32, super_res=1
// Pipeline: kA (W-rDFT keep 32) -> kB (H-DFT at 64 retained ky) -> kC (per-mode
// channel mix) -> kD (inverse H-DFT) -> kE (inverse W-rDFT + bias).
// All twiddles are e^{±2*pi*i*n/128}: one 128-entry cos/sin table in LDS.

__device__ __forceinline__ void build_tab(float* tabs) {
    int t = threadIdx.x;
    if (t < 128) {
        float ang = (float)t * 0.049087385212340517f;  // 2*pi/128
        float s, c;
        sincosf(ang, &s, &c);
        tabs[t] = c;        // cos at [0..127]
        tabs[129 + t] = s;  // sin at [129..256]  (129 offset de-correlates banks)
    }
}

// ---- kA: A[row=(b,ci,h)][2*kx+p] = rDFT_W(x)[kx], kx=0..31 ----------------
__global__ __launch_bounds__(256) void kA(const float* __restrict__ x,
                                          float* __restrict__ A) {
    __shared__ float tabs[258];
    __shared__ float xs[4][128];
    build_tab(tabs);
    int t = threadIdx.x;
    int wv = t >> 6, lane = t & 63;
    size_t row = (size_t)blockIdx.x * 4 + wv;  // 131072 rows
    const float* xr = x + row * 128;
    float2 v2 = *(const float2*)(xr + 2 * lane);
    xs[wv][2 * lane] = v2.x;
    xs[wv][2 * lane + 1] = v2.y;
    __syncthreads();
    int kx = lane & 31, p = lane >> 5;
    // fold w and w+64: exp(-i*pi*kx) = (-1)^kx
    float sgn = (kx & 1) ? -1.f : 1.f;
    const float* tab = p ? (tabs + 129) : tabs;
    float acc = 0.f;
    int idx = 0;
    #pragma unroll
    for (int w = 0; w < 64; ++w) {
        float v = fmaf(sgn, xs[wv][w + 64], xs[wv][w]);
        acc = fmaf(v, tab[idx], acc);
        idx = (idx + kx) & 127;
    }
    if (p) acc = -acc;  // im = -sum x*sin
    A[row * 64 + 2 * kx + p] = acc;
}

// ---- kB: XF[(b,ci)][j*32+kx] = sum_h A[h][kx]*e^{-2pi i ky(j) h/128} ------
// j=0..31 -> ky=j (top corner); j=32..63 -> ky=j+64 (bottom corner)
__global__ __launch_bounds__(256) void kB(const float* __restrict__ A,
                                          float* __restrict__ XF) {
    __shared__ float tabs[258];
    __shared__ float At[128 * 64];  // [h][2*kx+p], 32 KB
    build_tab(tabs);
    int t = threadIdx.x;
    size_t bc = blockIdx.x;  // b*64+ci, 1024 blocks
    const float4* src = (const float4*)(A + bc * 8192);
    float4* d4 = (float4*)At;
    #pragma unroll
    for (int i = 0; i < 8; ++i) d4[t + i * 256] = src[t + i * 256];
    __syncthreads();
    int j = t & 63;
    int kx0 = (t >> 6) * 8;
    int ky = (j < 32) ? j : j + 64;
    const float* cosT = tabs;
    const float* sinT = tabs + 129;
    float re[8] = {0, 0, 0, 0, 0, 0, 0, 0};
    float im[8] = {0, 0, 0, 0, 0, 0, 0, 0};
    int idx = 0;  // (ky*h) & 127
    for (int h = 0; h < 128; ++h) {
        float c = cosT[idx], s = sinT[idx];
        const float4* ap = (const float4*)(&At[h * 64 + 2 * kx0]);
        #pragma unroll
        for (int q4 = 0; q4 < 4; ++q4) {
            float4 av = ap[q4];  // (ar0, ai0, ar1, ai1)
            int q0 = 2 * q4, q1 = 2 * q4 + 1;
            // (ar+i*ai)*(c - i*s) = (ar*c + ai*s) + i*(ai*c - ar*s)
            re[q0] = fmaf(av.x, c, re[q0]); re[q0] = fmaf(av.y, s, re[q0]);
            im[q0] = fmaf(av.y, c, im[q0]); im[q0] = fmaf(-av.x, s, im[q0]);
            re[q1] = fmaf(av.z, c, re[q1]); re[q1] = fmaf(av.w, s, re[q1]);
            im[q1] = fmaf(av.w, c, im[q1]); im[q1] = fmaf(-av.z, s, im[q1]);
        }
        idx = (idx + ky) & 127;
    }
    float* dst = XF + bc * 4096 + (size_t)(j * 32 + kx0) * 2;
    #pragma unroll
    for (int q4 = 0; q4 < 4; ++q4) {
        ((float4*)dst)[q4] =
            make_float4(re[2 * q4], im[2 * q4], re[2 * q4 + 1], im[2 * q4 + 1]);
    }
}

// ---- kC: per-mode channel mix. block = (corner c, mode m). ----------------
// YF[b][co][c*1024+m] = sum_ci XF[b][ci][c*1024+m] * (W0 + i*W1)[c][ci][co][m]
__global__ __launch_bounds__(256) void kC(const float* __restrict__ XF,
                                          const float* __restrict__ Wgt,
                                          float* __restrict__ YF) {
    __shared__ float INs[2048];  // [f=b*64+ci][re,im], 8 KB
    __shared__ float Ws[8192];   // [g=ci*64+co][re,im], 32 KB
    int t = threadIdx.x;
    int c = blockIdx.x >> 10;
    int m = blockIdx.x & 1023;
    int slot = c * 1024 + m;
    #pragma unroll
    for (int s = 0; s < 4; ++s) {
        int f = t + s * 256;
        ((float2*)INs)[f] = *(const float2*)(XF + ((size_t)f * 2048 + slot) * 2);
    }
    #pragma unroll
    for (int s = 0; s < 16; ++s) {
        int g = t + s * 256;  // ci*64+co
        float wr = Wgt[(size_t)(c * 4096 + g) * 1024 + m];
        float wi = Wgt[(size_t)((2 + c) * 4096 + g) * 1024 + m];
        Ws[2 * g] = wr;
        Ws[2 * g + 1] = wi;
    }
    __syncthreads();
    int co0 = (t & 31) * 2;
    int b0 = (t >> 5) * 2;
    float o00r = 0, o00i = 0, o01r = 0, o01i = 0;
    float o10r = 0, o10i = 0, o11r = 0, o11i = 0;
    for (int ci = 0; ci < 64; ++ci) {
        float4 w4 = *(const float4*)(&Ws[(ci * 64 + co0) * 2]);  // wr0,wi0,wr1,wi1
        float2 i0 = *(const float2*)(&INs[(b0 * 64 + ci) * 2]);
        float2 i1 = *(const float2*)(&INs[((b0 + 1) * 64 + ci) * 2]);
        o00r = fmaf(i0.x, w4.x, o00r); o00r = fmaf(-i0.y, w4.y, o00r);
        o00i = fmaf(i0.x, w4.y, o00i); o00i = fmaf(i0.y, w4.x, o00i);
        o01r = fmaf(i0.x, w4.z, o01r); o01r = fmaf(-i0.y, w4.w, o01r);
        o01i = fmaf(i0.x, w4.w, o01i); o01i = fmaf(i0.y, w4.z, o01i);
        o10r = fmaf(i1.x, w4.x, o10r); o10r = fmaf(-i1.y, w4.y, o10r);
        o10i = fmaf(i1.x, w4.y, o10i); o10i = fmaf(i1.y, w4.x, o10i);
        o11r = fmaf(i1.x, w4.z, o11r); o11r = fmaf(-i1.y, w4.w, o11r);
        o11i = fmaf(i1.x, w4.w, o11i); o11i = fmaf(i1.y, w4.z, o11i);
    }
    *(float2*)(YF + ((size_t)(b0 * 64 + co0) * 2048 + slot) * 2) = make_float2(o00r, o00i);
    *(float2*)(YF + ((size_t)(b0 * 64 + co0 + 1) * 2048 + slot) * 2) = make_float2(o01r, o01i);
    *(float2*)(YF + ((size_t)((b0 + 1) * 64 + co0) * 2048 + slot) * 2) = make_float2(o10r, o10i);
    *(float2*)(YF + ((size_t)((b0 + 1) * 64 + co0 + 1) * 2048 + slot) * 2) = make_float2(o11r, o11i);
}

// ---- kD: Z[(b,co)][h][kx] = sum_j YF[j][kx]*e^{+2pi i h ky(j)/128} --------
__global__ __launch_bounds__(256) void kD(const float* __restrict__ YF,
                                          float* __restrict__ Z) {
    __shared__ float tabs[258];
    __shared__ float Ys[4096];  // [j][kx][re,im], 16 KB
    build_tab(tabs);
    int t = threadIdx.x;
    size_t bo = blockIdx.x;  // b*64+co, 1024 blocks
    const float4* src = (const float4*)(YF + bo * 4096);
    #pragma unroll
    for (int i = 0; i < 4; ++i) ((float4*)Ys)[t + i * 256] = src[t + i * 256];
    __syncthreads();
    int hl = t & 63;            // h and h+64 via (-1)^ky
    int kx0 = (t >> 6) * 8;
    const float* cosT = tabs;
    const float* sinT = tabs + 129;
    float ar[8] = {0,0,0,0,0,0,0,0}, ai[8] = {0,0,0,0,0,0,0,0};
    float br[8] = {0,0,0,0,0,0,0,0}, bi[8] = {0,0,0,0,0,0,0,0};
    int idx = 0;  // (ky(j)*hl) & 127
    for (int j = 0; j < 64; ++j) {
        int ky = (j < 32) ? j : j + 64;
        float cc = cosT[idx], ss = sinT[idx];
        float sg = (ky & 1) ? -1.f : 1.f;  // tw(h+64) = (-1)^ky * tw(h)
        float c2 = sg * cc, s2 = sg * ss;
        const float4* yp = (const float4*)(&Ys[(j * 32 + kx0) * 2]);
        #pragma unroll
        for (int q4 = 0; q4 < 4; ++q4) {
            float4 v = yp[q4];  // (yr0, yi0, yr1, yi1)
            int q0 = 2 * q4, q1 = 2 * q4 + 1;
            // (yr+i*yi)*(c + i*s) = (yr*c - yi*s) + i*(yr*s + yi*c)
            ar[q0] = fmaf(v.x, cc, ar[q0]); ar[q0] = fmaf(-v.y, ss, ar[q0]);
            ai[q0] = fmaf(v.x, ss, ai[q0]); ai[q0] = fmaf(v.y, cc, ai[q0]);
            br[q0] = fmaf(v.x, c2, br[q0]); br[q0] = fmaf(-v.y, s2, br[q0]);
            bi[q0] = fmaf(v.x, s2, bi[q0]); bi[q0] = fmaf(v.y, c2, bi[q0]);
            ar[q1] = fmaf(v.z, cc, ar[q1]); ar[q1] = fmaf(-v.w, ss, ar[q1]);
            ai[q1] = fmaf(v.z, ss, ai[q1]); ai[q1] = fmaf(v.w, cc, ai[q1]);
            br[q1] = fmaf(v.z, c2, br[q1]); br[q1] = fmaf(-v.w, s2, br[q1]);
            bi[q1] = fmaf(v.z, s2, bi[q1]); bi[q1] = fmaf(v.w, c2, bi[q1]);
        }
        idx = (idx + hl) & 127;
        if (j == 31) idx = (idx + ((hl & 1) << 6)) & 127;  // ky jumps 31->96
    }
    float* d0 = Z + (bo * 128 + hl) * 64 + kx0 * 2;
    float* d1 = Z + (bo * 128 + hl + 64) * 64 + kx0 * 2;
    #pragma unroll
    for (int q4 = 0; q4 < 4; ++q4) {
        ((float4*)d0)[q4] = make_float4(ar[2*q4], ai[2*q4], ar[2*q4+1], ai[2*q4+1]);
        ((float4*)d1)[q4] = make_float4(br[2*q4], bi[2*q4], br[2*q4+1], bi[2*q4+1]);
    }
}

// ---- kE: y[row][w] = (1/16384)*(Re(Z0) + 2*sum_{k=1..31} Re(Zk e^{i th})) + bias
// (pocketfft c2r drops Im of the DC bin; kx<=31 so no Nyquist term)
__global__ __launch_bounds__(256) void kE(const float* __restrict__ Z,
                                          const float* __restrict__ bias,
                                          float* __restrict__ out) {
    __shared__ float tabs[258];
    __shared__ float zs[4][64];
    build_tab(tabs);
    int t = threadIdx.x;
    int wv = t >> 6, lane = t & 63;
    size_t row = (size_t)blockIdx.x * 4 + wv;  // (b,co,h) rows = 131072
    int co = ((int)(row >> 7)) & 63;
    zs[wv][lane] = Z[row * 64 + lane];
    __syncthreads();
    const float* cosT = tabs;
    const float* sinT = tabs + 129;
    float Se = 0.f, So = 0.f;  // even-k / odd-k partial sums (w vs w+64 share)
    int idx = lane;            // (k*lane) & 127, k starts at 1
    #pragma unroll
    for (int k = 1; k < 32; ++k) {
        float c = cosT[idx], s = sinT[idx];
        float zr_ = zs[wv][2 * k], zi_ = zs[wv][2 * k + 1];
        if (k & 1) { So = fmaf(zr_, c, So); So = fmaf(-zi_, s, So); }
        else       { Se = fmaf(zr_, c, Se); Se = fmaf(-zi_, s, Se); }
        idx = (idx + lane) & 127;
    }
    float dc = zs[wv][0];
    float bv = bias[co];
    const float inv = 6.103515625e-05f;  // 1/16384
    float y0 = fmaf(2.f * (Se + So), inv, dc * inv) + bv;  // w = lane
    float y1 = fmaf(2.f * (Se - So), inv, dc * inv) + bv;  // w = lane+64
    out[row * 128 + lane] = y0;
    out[row * 128 + 64 + lane] = y1;
}

extern "C" void kernel_launch(void* const* d_in, const int* in_sizes, int n_in,
                              void* d_out, int out_size, void* d_ws, size_t ws_size,
                              hipStream_t stream) {
    (void)in_sizes; (void)n_in; (void)out_size; (void)ws_size;
    const float* x    = (const float*)d_in[0];
    const float* wgt  = (const float*)d_in[1];
    const float* bias = (const float*)d_in[2];
    // d_in[3] = super_res, always 1 for this problem
    float* outp  = (float*)d_out;
    float* bufA  = (float*)d_ws;                            // 32 MiB
    float* bufXF = (float*)((char*)d_ws + 33554432);        // 16 MiB
    float* bufYF = (float*)((char*)d_ws + 50331648);        // 16 MiB
    float* bufZ  = bufA;                                    // reuse A
    hipLaunchKernelGGL(kA, dim3(32768), dim3(256), 0, stream, x, bufA);
    hipLaunchKernelGGL(kB, dim3(1024), dim3(256), 0, stream, bufA, bufXF);
    hipLaunchKernelGGL(kC, dim3(2048), dim3(256), 0, stream, bufXF, wgt, bufYF);
    hipLaunchKernelGGL(kD, dim3(1024), dim3(256), 0, stream, bufYF, bufZ);
    hipLaunchKernelGGL(kE, dim3(32768), dim3(256), 0, stream, bufZ, bias, outp);
}

// Round 3
// 283.211 us; speedup vs baseline: 1.5693x; 1.5693x over previous
//
#include <hip/hip_runtime.h>

// FactorizedSpectralConv2d: B=16, CIN=COUT=64, H=W=128, MH=MW=32, super_res=1
// Pipeline: kA (W-rDFT keep 32) -> kB (H-DFT at 64 retained ky) -> kC (per-mode
// channel mix) -> kD (inverse H-DFT) -> kE (inverse W-rDFT + bias).
// All twiddles are e^{±2*pi*i*n/128}: one 128-entry cos/sin table in LDS.

__device__ __forceinline__ void build_tab(float* tabs) {
    int t = threadIdx.x;
    if (t < 128) {
        float ang = (float)t * 0.049087385212340517f;  // 2*pi/128
        float s, c;
        sincosf(ang, &s, &c);
        tabs[t] = c;        // cos at [0..127]
        tabs[129 + t] = s;  // sin at [129..256]  (129 offset de-correlates banks)
    }
}

// ---- kA: A[row=(b,ci,h)][2*kx+p] = rDFT_W(x)[kx], kx=0..31 ----------------
__global__ __launch_bounds__(256) void kA(const float* __restrict__ x,
                                          float* __restrict__ A) {
    __shared__ float tabs[258];
    __shared__ float xs[4][128];
    build_tab(tabs);
    int t = threadIdx.x;
    int wv = t >> 6, lane = t & 63;
    size_t row = (size_t)blockIdx.x * 4 + wv;  // 131072 rows
    const float* xr = x + row * 128;
    float2 v2 = *(const float2*)(xr + 2 * lane);
    xs[wv][2 * lane] = v2.x;
    xs[wv][2 * lane + 1] = v2.y;
    __syncthreads();
    int kx = lane & 31, p = lane >> 5;
    // fold w and w+64: exp(-i*pi*kx) = (-1)^kx
    float sgn = (kx & 1) ? -1.f : 1.f;
    const float* tab = p ? (tabs + 129) : tabs;
    float acc = 0.f;
    int idx = 0;
    #pragma unroll
    for (int w = 0; w < 64; ++w) {
        float v = fmaf(sgn, xs[wv][w + 64], xs[wv][w]);
        acc = fmaf(v, tab[idx], acc);
        idx = (idx + kx) & 127;
    }
    if (p) acc = -acc;  // im = -sum x*sin
    A[row * 64 + 2 * kx + p] = acc;
}

// ---- kB: XF[(b,ci)][j*32+kx] = sum_h A[h][kx]*e^{-2pi i ky(j) h/128} ------
// j=0..31 -> ky=j (top corner); j=32..63 -> ky=j+64 (bottom corner)
__global__ __launch_bounds__(256) void kB(const float* __restrict__ A,
                                          float* __restrict__ XF) {
    __shared__ float tabs[258];
    __shared__ float At[128 * 64];  // [h][2*kx+p], 32 KB
    build_tab(tabs);
    int t = threadIdx.x;
    size_t bc = blockIdx.x;  // b*64+ci, 1024 blocks
    const float4* src = (const float4*)(A + bc * 8192);
    float4* d4 = (float4*)At;
    #pragma unroll
    for (int i = 0; i < 8; ++i) d4[t + i * 256] = src[t + i * 256];
    __syncthreads();
    int j = t & 63;
    int kx0 = (t >> 6) * 8;
    int ky = (j < 32) ? j : j + 64;
    const float* cosT = tabs;
    const float* sinT = tabs + 129;
    float re[8] = {0, 0, 0, 0, 0, 0, 0, 0};
    float im[8] = {0, 0, 0, 0, 0, 0, 0, 0};
    int idx = 0;  // (ky*h) & 127
    for (int h = 0; h < 128; ++h) {
        float c = cosT[idx], s = sinT[idx];
        const float4* ap = (const float4*)(&At[h * 64 + 2 * kx0]);
        #pragma unroll
        for (int q4 = 0; q4 < 4; ++q4) {
            float4 av = ap[q4];  // (ar0, ai0, ar1, ai1)
            int q0 = 2 * q4, q1 = 2 * q4 + 1;
            // (ar+i*ai)*(c - i*s) = (ar*c + ai*s) + i*(ai*c - ar*s)
            re[q0] = fmaf(av.x, c, re[q0]); re[q0] = fmaf(av.y, s, re[q0]);
            im[q0] = fmaf(av.y, c, im[q0]); im[q0] = fmaf(-av.x, s, im[q0]);
            re[q1] = fmaf(av.z, c, re[q1]); re[q1] = fmaf(av.w, s, re[q1]);
            im[q1] = fmaf(av.w, c, im[q1]); im[q1] = fmaf(-av.z, s, im[q1]);
        }
        idx = (idx + ky) & 127;
    }
    float* dst = XF + bc * 4096 + (size_t)(j * 32 + kx0) * 2;
    #pragma unroll
    for (int q4 = 0; q4 < 4; ++q4) {
        ((float4*)dst)[q4] =
            make_float4(re[2 * q4], im[2 * q4], re[2 * q4 + 1], im[2 * q4 + 1]);
    }
}

// ---- kC: per-mode channel mix, coalesced-weight version. ------------------
// block = (c, my, co-tile of 16, mx-half of 16); all 16 b in-block so each
// weight element is read exactly once, contiguously along mx.
// Rows of XF/YF are 2048 complex modes: slot = (c*32+my)*32 + mx_global.
__global__ __launch_bounds__(256) void kC(const float* __restrict__ XF,
                                          const float* __restrict__ Wgt,
                                          float* __restrict__ YF) {
    __shared__ float2 Xs[8 * 16 * 16];  // [ci_l][b][mx], 16 KB
    __shared__ float2 Ws[8 * 16 * 16];  // [ci_l][co_l][mx], 16 KB
    int t = threadIdx.x;
    int bid = blockIdx.x;            // 512 = c(1b)<<8 | my(5b)<<3 | cot(2b)<<1 | mxh(1b)
    int mxh = bid & 1;
    int cot = (bid >> 1) & 3;
    int my  = (bid >> 3) & 31;
    int c   = bid >> 8;
    int co0 = cot * 16;
    int slotbase = (c * 32 + my) * 32 + mxh * 16;  // + mx, in [0,2048)
    int mx = t & 15;
    int b  = t >> 4;
    float2 acc[16];
    #pragma unroll
    for (int i = 0; i < 16; ++i) acc[i] = make_float2(0.f, 0.f);
    const size_t wre_base = (size_t)c * 4096 * 1024 + (size_t)my * 32 + mxh * 16;
    const size_t wim_base = wre_base + (size_t)2 * 4096 * 1024;
    for (int cc = 0; cc < 8; ++cc) {
        __syncthreads();
        #pragma unroll
        for (int s = 0; s < 8; ++s) {  // X chunk: 8ci x 16b x 16mx
            int e = t + s * 256;
            int emx = e & 15, eb = (e >> 4) & 15, eci = e >> 8;
            int ci = cc * 8 + eci;
            Xs[e] = *(const float2*)(XF + ((size_t)(eb * 64 + ci) * 2048 + slotbase + emx) * 2);
        }
        #pragma unroll
        for (int s = 0; s < 8; ++s) {  // W chunk: 8ci x 16co x 16mx (re+im)
            int e = t + s * 256;
            int emx = e & 15, eco = (e >> 4) & 15, eci = e >> 8;
            size_t g = (size_t)(cc * 8 + eci) * 64 + co0 + eco;
            float wr = Wgt[wre_base + g * 1024 + emx];
            float wi = Wgt[wim_base + g * 1024 + emx];
            Ws[e] = make_float2(wr, wi);
        }
        __syncthreads();
        #pragma unroll
        for (int ci_l = 0; ci_l < 8; ++ci_l) {
            float2 xv = Xs[(ci_l * 16 + b) * 16 + mx];
            #pragma unroll
            for (int co_l = 0; co_l < 16; ++co_l) {
                float2 w = Ws[(ci_l * 16 + co_l) * 16 + mx];  // broadcast across b-groups
                acc[co_l].x = fmaf(xv.x, w.x, acc[co_l].x);
                acc[co_l].x = fmaf(-xv.y, w.y, acc[co_l].x);
                acc[co_l].y = fmaf(xv.x, w.y, acc[co_l].y);
                acc[co_l].y = fmaf(xv.y, w.x, acc[co_l].y);
            }
        }
    }
    #pragma unroll
    for (int co_l = 0; co_l < 16; ++co_l) {
        *(float2*)(YF + ((size_t)(b * 64 + co0 + co_l) * 2048 + slotbase + mx) * 2) = acc[co_l];
    }
}

// ---- kD: Z[(b,co)][h][kx] = sum_j YF[j][kx]*e^{+2pi i h ky(j)/128} --------
__global__ __launch_bounds__(256) void kD(const float* __restrict__ YF,
                                          float* __restrict__ Z) {
    __shared__ float tabs[258];
    __shared__ float Ys[4096];  // [j][kx][re,im], 16 KB
    build_tab(tabs);
    int t = threadIdx.x;
    size_t bo = blockIdx.x;  // b*64+co, 1024 blocks
    const float4* src = (const float4*)(YF + bo * 4096);
    #pragma unroll
    for (int i = 0; i < 4; ++i) ((float4*)Ys)[t + i * 256] = src[t + i * 256];
    __syncthreads();
    int hl = t & 63;            // h and h+64 via (-1)^ky
    int kx0 = (t >> 6) * 8;
    const float* cosT = tabs;
    const float* sinT = tabs + 129;
    float ar[8] = {0,0,0,0,0,0,0,0}, ai[8] = {0,0,0,0,0,0,0,0};
    float br[8] = {0,0,0,0,0,0,0,0}, bi[8] = {0,0,0,0,0,0,0,0};
    int idx = 0;  // (ky(j)*hl) & 127
    for (int j = 0; j < 64; ++j) {
        int ky = (j < 32) ? j : j + 64;
        float cc = cosT[idx], ss = sinT[idx];
        float sg = (ky & 1) ? -1.f : 1.f;  // tw(h+64) = (-1)^ky * tw(h)
        float c2 = sg * cc, s2 = sg * ss;
        const float4* yp = (const float4*)(&Ys[(j * 32 + kx0) * 2]);
        #pragma unroll
        for (int q4 = 0; q4 < 4; ++q4) {
            float4 v = yp[q4];  // (yr0, yi0, yr1, yi1)
            int q0 = 2 * q4, q1 = 2 * q4 + 1;
            // (yr+i*yi)*(c + i*s) = (yr*c - yi*s) + i*(yr*s + yi*c)
            ar[q0] = fmaf(v.x, cc, ar[q0]); ar[q0] = fmaf(-v.y, ss, ar[q0]);
            ai[q0] = fmaf(v.x, ss, ai[q0]); ai[q0] = fmaf(v.y, cc, ai[q0]);
            br[q0] = fmaf(v.x, c2, br[q0]); br[q0] = fmaf(-v.y, s2, br[q0]);
            bi[q0] = fmaf(v.x, s2, bi[q0]); bi[q0] = fmaf(v.y, c2, bi[q0]);
            ar[q1] = fmaf(v.z, cc, ar[q1]); ar[q1] = fmaf(-v.w, ss, ar[q1]);
            ai[q1] = fmaf(v.z, ss, ai[q1]); ai[q1] = fmaf(v.w, cc, ai[q1]);
            br[q1] = fmaf(v.z, c2, br[q1]); br[q1] = fmaf(-v.w, s2, br[q1]);
            bi[q1] = fmaf(v.z, s2, bi[q1]); bi[q1] = fmaf(v.w, c2, bi[q1]);
        }
        idx = (idx + hl) & 127;
        if (j == 31) idx = (idx + ((hl & 1) << 6)) & 127;  // ky jumps 31->96
    }
    float* d0 = Z + (bo * 128 + hl) * 64 + kx0 * 2;
    float* d1 = Z + (bo * 128 + hl + 64) * 64 + kx0 * 2;
    #pragma unroll
    for (int q4 = 0; q4 < 4; ++q4) {
        ((float4*)d0)[q4] = make_float4(ar[2*q4], ai[2*q4], ar[2*q4+1], ai[2*q4+1]);
        ((float4*)d1)[q4] = make_float4(br[2*q4], bi[2*q4], br[2*q4+1], bi[2*q4+1]);
    }
}

// ---- kE: y[row][w] = (1/16384)*(Re(Z0) + 2*sum_{k=1..31} Re(Zk e^{i th})) + bias
// (pocketfft c2r drops Im of the DC bin; kx<=31 so no Nyquist term)
__global__ __launch_bounds__(256) void kE(const float* __restrict__ Z,
                                          const float* __restrict__ bias,
                                          float* __restrict__ out) {
    __shared__ float tabs[258];
    __shared__ float zs[4][64];
    build_tab(tabs);
    int t = threadIdx.x;
    int wv = t >> 6, lane = t & 63;
    size_t row = (size_t)blockIdx.x * 4 + wv;  // (b,co,h) rows = 131072
    int co = ((int)(row >> 7)) & 63;
    zs[wv][lane] = Z[row * 64 + lane];
    __syncthreads();
    const float* cosT = tabs;
    const float* sinT = tabs + 129;
    float Se = 0.f, So = 0.f;  // even-k / odd-k partial sums (w vs w+64 share)
    int idx = lane;            // (k*lane) & 127, k starts at 1
    #pragma unroll
    for (int k = 1; k < 32; ++k) {
        float c = cosT[idx], s = sinT[idx];
        float zr_ = zs[wv][2 * k], zi_ = zs[wv][2 * k + 1];
        if (k & 1) { So = fmaf(zr_, c, So); So = fmaf(-zi_, s, So); }
        else       { Se = fmaf(zr_, c, Se); Se = fmaf(-zi_, s, Se); }
        idx = (idx + lane) & 127;
    }
    float dc = zs[wv][0];
    float bv = bias[co];
    const float inv = 6.103515625e-05f;  // 1/16384
    float y0 = fmaf(2.f * (Se + So), inv, dc * inv) + bv;  // w = lane
    float y1 = fmaf(2.f * (Se - So), inv, dc * inv) + bv;  // w = lane+64
    out[row * 128 + lane] = y0;
    out[row * 128 + 64 + lane] = y1;
}

extern "C" void kernel_launch(void* const* d_in, const int* in_sizes, int n_in,
                              void* d_out, int out_size, void* d_ws, size_t ws_size,
                              hipStream_t stream) {
    (void)in_sizes; (void)n_in; (void)out_size; (void)ws_size;
    const float* x    = (const float*)d_in[0];
    const float* wgt  = (const float*)d_in[1];
    const float* bias = (const float*)d_in[2];
    // d_in[3] = super_res, always 1 for this problem
    float* outp  = (float*)d_out;
    float* bufA  = (float*)d_ws;                            // 32 MiB
    float* bufXF = (float*)((char*)d_ws + 33554432);        // 16 MiB
    float* bufYF = (float*)((char*)d_ws + 50331648);        // 16 MiB
    float* bufZ  = bufA;                                    // reuse A
    hipLaunchKernelGGL(kA, dim3(32768), dim3(256), 0, stream, x, bufA);
    hipLaunchKernelGGL(kB, dim3(1024), dim3(256), 0, stream, bufA, bufXF);
    hipLaunchKernelGGL(kC, dim3(512), dim3(256), 0, stream, bufXF, wgt, bufYF);
    hipLaunchKernelGGL(kD, dim3(1024), dim3(256), 0, stream, bufYF, bufZ);
    hipLaunchKernelGGL(kE, dim3(32768), dim3(256), 0, stream, bufZ, bias, outp);
}

// Round 4
// 233.934 us; speedup vs baseline: 1.8999x; 1.2106x over previous
//
#include <hip/hip_runtime.h>

// FactorizedSpectralConv2d: B=16, CIN=COUT=64, H=W=128, MH=MW=32, super_res=1
// Pipeline: kA (W-rDFT keep 32, GEMM-style) -> kB (H-DFT at 64 retained ky) ->
// kC (per-mode channel mix) -> kD (inverse H-DFT) -> kE (inverse W-rDFT + bias).

__device__ __forceinline__ void build_tab(float* tabs) {
    int t = threadIdx.x;
    if (t < 128) {
        float ang = (float)t * 0.049087385212340517f;  // 2*pi/128
        float s, c;
        sincosf(ang, &s, &c);
        tabs[t] = c;        // cos at [0..127]
        tabs[129 + t] = s;  // sin at [129..256]
    }
}

// ---- kA: A[row=(b,ci,h)][q=2kx+p] = rDFT_W(x)[kx], kx=0..31 ---------------
// GEMM-style: xeo[w][h]=(ve,vo) folded+transposed in LDS (stride 132 floats),
// Twid[w][q] = q&1 ? -sin(2pi w kx/128) : cos(...), kx=q>>1.
// Block = (b*64+ci, h-half): 2048 blocks. Thread tile: 4h x 4q, 16 fma / 3 b128.
__global__ __launch_bounds__(256) void kA(const float* __restrict__ x,
                                          float* __restrict__ A) {
    __shared__ __align__(16) float xeo[64 * 132];   // 33.8 KB
    __shared__ __align__(16) float Twid[64 * 64];   // 16 KB
    int t = threadIdx.x;
    int bid = blockIdx.x;
    size_t bc = bid >> 1;
    int hbase = (bid & 1) << 6;
    // Twiddle precompute (4096 entries)
    #pragma unroll
    for (int i = 0; i < 16; ++i) {
        int e = t + i * 256;
        int w = e >> 6, q = e & 63, kx = q >> 1;
        int idx = (w * kx) & 127;
        float ang = (float)idx * 0.049087385212340517f;
        float s, c;
        sincosf(ang, &s, &c);
        Twid[e] = (q & 1) ? -s : c;
    }
    // Stage + fold + transpose: x[h][w], x[h][w+64] -> xeo[w][h] = (ve, vo)
    const float* xb = x + bc * 16384 + (size_t)hbase * 128;
    int w4 = (t & 15) * 4;
    #pragma unroll
    for (int it = 0; it < 4; ++it) {
        int h = it * 16 + (t >> 4);
        float4 lo = *(const float4*)(xb + h * 128 + w4);
        float4 hi = *(const float4*)(xb + h * 128 + w4 + 64);
        ((float2*)&xeo[(w4 + 0) * 132])[h] = make_float2(lo.x + hi.x, lo.x - hi.x);
        ((float2*)&xeo[(w4 + 1) * 132])[h] = make_float2(lo.y + hi.y, lo.y - hi.y);
        ((float2*)&xeo[(w4 + 2) * 132])[h] = make_float2(lo.z + hi.z, lo.z - hi.z);
        ((float2*)&xeo[(w4 + 3) * 132])[h] = make_float2(lo.w + hi.w, lo.w - hi.w);
    }
    __syncthreads();
    int l = t & 63, wv = t >> 6;
    int h0 = (l & 15) * 4;              // block-local h
    int q0 = wv * 16 + (l >> 4) * 4;    // multiple of 4; kx pair (q0/2, q0/2+1)
    float4 acc0 = {0,0,0,0}, acc1 = {0,0,0,0}, acc2 = {0,0,0,0}, acc3 = {0,0,0,0};
    const float4* xv = (const float4*)xeo;   // 33 float4 per w-row
    const float4* tv = (const float4*)Twid;  // 16 float4 per w-row
    int xoff = 2 * (l & 15);
    int toff = q0 >> 2;
    for (int w = 0; w < 64; ++w) {
        float4 d0 = xv[w * 33 + xoff];      // ve(h0),vo(h0),ve(h0+1),vo(h0+1)
        float4 d1 = xv[w * 33 + xoff + 1];  // h0+2, h0+3
        float4 tw = tv[w * 16 + toff];      // Tc(kxe),Ts(kxe),Tc(kxo),Ts(kxo)
        acc0.x = fmaf(d0.x, tw.x, acc0.x); acc0.y = fmaf(d0.x, tw.y, acc0.y);
        acc0.z = fmaf(d0.y, tw.z, acc0.z); acc0.w = fmaf(d0.y, tw.w, acc0.w);
        acc1.x = fmaf(d0.z, tw.x, acc1.x); acc1.y = fmaf(d0.z, tw.y, acc1.y);
        acc1.z = fmaf(d0.w, tw.z, acc1.z); acc1.w = fmaf(d0.w, tw.w, acc1.w);
        acc2.x = fmaf(d1.x, tw.x, acc2.x); acc2.y = fmaf(d1.x, tw.y, acc2.y);
        acc2.z = fmaf(d1.y, tw.z, acc2.z); acc2.w = fmaf(d1.y, tw.w, acc2.w);
        acc3.x = fmaf(d1.z, tw.x, acc3.x); acc3.y = fmaf(d1.z, tw.y, acc3.y);
        acc3.z = fmaf(d1.w, tw.z, acc3.z); acc3.w = fmaf(d1.w, tw.w, acc3.w);
    }
    float* Ab = A + (bc * 128 + hbase + h0) * 64 + q0;
    *(float4*)(Ab)       = acc0;
    *(float4*)(Ab + 64)  = acc1;
    *(float4*)(Ab + 128) = acc2;
    *(float4*)(Ab + 192) = acc3;
}

// ---- kB: XF[(b,ci)][j*32+kx] = sum_h A[h][kx]*e^{-2pi i ky(j) h/128} ------
// j=0..31 -> ky=j (top corner); j=32..63 -> ky=j+64 (bottom corner)
__global__ __launch_bounds__(256) void kB(const float* __restrict__ A,
                                          float* __restrict__ XF) {
    __shared__ float tabs[258];
    __shared__ float At[128 * 64];  // [h][2*kx+p], 32 KB
    build_tab(tabs);
    int t = threadIdx.x;
    size_t bc = blockIdx.x;  // b*64+ci, 1024 blocks
    const float4* src = (const float4*)(A + bc * 8192);
    float4* d4 = (float4*)At;
    #pragma unroll
    for (int i = 0; i < 8; ++i) d4[t + i * 256] = src[t + i * 256];
    __syncthreads();
    int j = t & 63;
    int kx0 = (t >> 6) * 8;
    int ky = (j < 32) ? j : j + 64;
    const float* cosT = tabs;
    const float* sinT = tabs + 129;
    float re[8] = {0, 0, 0, 0, 0, 0, 0, 0};
    float im[8] = {0, 0, 0, 0, 0, 0, 0, 0};
    int idx = 0;  // (ky*h) & 127
    for (int h = 0; h < 128; ++h) {
        float c = cosT[idx], s = sinT[idx];
        const float4* ap = (const float4*)(&At[h * 64 + 2 * kx0]);
        #pragma unroll
        for (int q4 = 0; q4 < 4; ++q4) {
            float4 av = ap[q4];  // (ar0, ai0, ar1, ai1)
            int q0 = 2 * q4, q1 = 2 * q4 + 1;
            re[q0] = fmaf(av.x, c, re[q0]); re[q0] = fmaf(av.y, s, re[q0]);
            im[q0] = fmaf(av.y, c, im[q0]); im[q0] = fmaf(-av.x, s, im[q0]);
            re[q1] = fmaf(av.z, c, re[q1]); re[q1] = fmaf(av.w, s, re[q1]);
            im[q1] = fmaf(av.w, c, im[q1]); im[q1] = fmaf(-av.z, s, im[q1]);
        }
        idx = (idx + ky) & 127;
    }
    float* dst = XF + bc * 4096 + (size_t)(j * 32 + kx0) * 2;
    #pragma unroll
    for (int q4 = 0; q4 < 4; ++q4) {
        ((float4*)dst)[q4] =
            make_float4(re[2 * q4], im[2 * q4], re[2 * q4 + 1], im[2 * q4 + 1]);
    }
}

// ---- kC: per-mode channel mix, coalesced-weight version. ------------------
__global__ __launch_bounds__(256) void kC(const float* __restrict__ XF,
                                          const float* __restrict__ Wgt,
                                          float* __restrict__ YF) {
    __shared__ float2 Xs[8 * 16 * 16];  // [ci_l][b][mx], 16 KB
    __shared__ float2 Ws[8 * 16 * 16];  // [ci_l][co_l][mx], 16 KB
    int t = threadIdx.x;
    int bid = blockIdx.x;            // 512 = c(1b)<<8 | my(5b)<<3 | cot(2b)<<1 | mxh(1b)
    int mxh = bid & 1;
    int cot = (bid >> 1) & 3;
    int my  = (bid >> 3) & 31;
    int c   = bid >> 8;
    int co0 = cot * 16;
    int slotbase = (c * 32 + my) * 32 + mxh * 16;  // + mx, in [0,2048)
    int mx = t & 15;
    int b  = t >> 4;
    float2 acc[16];
    #pragma unroll
    for (int i = 0; i < 16; ++i) acc[i] = make_float2(0.f, 0.f);
    const size_t wre_base = (size_t)c * 4096 * 1024 + (size_t)my * 32 + mxh * 16;
    const size_t wim_base = wre_base + (size_t)2 * 4096 * 1024;
    for (int cc = 0; cc < 8; ++cc) {
        __syncthreads();
        #pragma unroll
        for (int s = 0; s < 8; ++s) {  // X chunk: 8ci x 16b x 16mx
            int e = t + s * 256;
            int emx = e & 15, eb = (e >> 4) & 15, eci = e >> 8;
            int ci = cc * 8 + eci;
            Xs[e] = *(const float2*)(XF + ((size_t)(eb * 64 + ci) * 2048 + slotbase + emx) * 2);
        }
        #pragma unroll
        for (int s = 0; s < 8; ++s) {  // W chunk: 8ci x 16co x 16mx (re+im)
            int e = t + s * 256;
            int emx = e & 15, eco = (e >> 4) & 15, eci = e >> 8;
            size_t g = (size_t)(cc * 8 + eci) * 64 + co0 + eco;
            float wr = Wgt[wre_base + g * 1024 + emx];
            float wi = Wgt[wim_base + g * 1024 + emx];
            Ws[e] = make_float2(wr, wi);
        }
        __syncthreads();
        #pragma unroll
        for (int ci_l = 0; ci_l < 8; ++ci_l) {
            float2 xv = Xs[(ci_l * 16 + b) * 16 + mx];
            #pragma unroll
            for (int co_l = 0; co_l < 16; ++co_l) {
                float2 w = Ws[(ci_l * 16 + co_l) * 16 + mx];
                acc[co_l].x = fmaf(xv.x, w.x, acc[co_l].x);
                acc[co_l].x = fmaf(-xv.y, w.y, acc[co_l].x);
                acc[co_l].y = fmaf(xv.x, w.y, acc[co_l].y);
                acc[co_l].y = fmaf(xv.y, w.x, acc[co_l].y);
            }
        }
    }
    #pragma unroll
    for (int co_l = 0; co_l < 16; ++co_l) {
        *(float2*)(YF + ((size_t)(b * 64 + co0 + co_l) * 2048 + slotbase + mx) * 2) = acc[co_l];
    }
}

// ---- kD: Z[(b,co)][h][kx] = sum_j YF[j][kx]*e^{+2pi i h ky(j)/128} --------
__global__ __launch_bounds__(256) void kD(const float* __restrict__ YF,
                                          float* __restrict__ Z) {
    __shared__ float tabs[258];
    __shared__ float Ys[4096];  // [j][kx][re,im], 16 KB
    build_tab(tabs);
    int t = threadIdx.x;
    size_t bo = blockIdx.x;  // b*64+co, 1024 blocks
    const float4* src = (const float4*)(YF + bo * 4096);
    #pragma unroll
    for (int i = 0; i < 4; ++i) ((float4*)Ys)[t + i * 256] = src[t + i * 256];
    __syncthreads();
    int hl = t & 63;            // h and h+64 via (-1)^ky
    int kx0 = (t >> 6) * 8;
    const float* cosT = tabs;
    const float* sinT = tabs + 129;
    float ar[8] = {0,0,0,0,0,0,0,0}, ai[8] = {0,0,0,0,0,0,0,0};
    float br[8] = {0,0,0,0,0,0,0,0}, bi[8] = {0,0,0,0,0,0,0,0};
    int idx = 0;  // (ky(j)*hl) & 127
    for (int j = 0; j < 64; ++j) {
        int ky = (j < 32) ? j : j + 64;
        float cc = cosT[idx], ss = sinT[idx];
        float sg = (ky & 1) ? -1.f : 1.f;
        float c2 = sg * cc, s2 = sg * ss;
        const float4* yp = (const float4*)(&Ys[(j * 32 + kx0) * 2]);
        #pragma unroll
        for (int q4 = 0; q4 < 4; ++q4) {
            float4 v = yp[q4];  // (yr0, yi0, yr1, yi1)
            int q0 = 2 * q4, q1 = 2 * q4 + 1;
            ar[q0] = fmaf(v.x, cc, ar[q0]); ar[q0] = fmaf(-v.y, ss, ar[q0]);
            ai[q0] = fmaf(v.x, ss, ai[q0]); ai[q0] = fmaf(v.y, cc, ai[q0]);
            br[q0] = fmaf(v.x, c2, br[q0]); br[q0] = fmaf(-v.y, s2, br[q0]);
            bi[q0] = fmaf(v.x, s2, bi[q0]); bi[q0] = fmaf(v.y, c2, bi[q0]);
            ar[q1] = fmaf(v.z, cc, ar[q1]); ar[q1] = fmaf(-v.w, ss, ar[q1]);
            ai[q1] = fmaf(v.z, ss, ai[q1]); ai[q1] = fmaf(v.w, cc, ai[q1]);
            br[q1] = fmaf(v.z, c2, br[q1]); br[q1] = fmaf(-v.w, s2, br[q1]);
            bi[q1] = fmaf(v.z, s2, bi[q1]); bi[q1] = fmaf(v.w, c2, bi[q1]);
        }
        idx = (idx + hl) & 127;
        if (j == 31) idx = (idx + ((hl & 1) << 6)) & 127;  // ky jumps 31->96
    }
    float* d0 = Z + (bo * 128 + hl) * 64 + kx0 * 2;
    float* d1 = Z + (bo * 128 + hl + 64) * 64 + kx0 * 2;
    #pragma unroll
    for (int q4 = 0; q4 < 4; ++q4) {
        ((float4*)d0)[q4] = make_float4(ar[2*q4], ai[2*q4], ar[2*q4+1], ai[2*q4+1]);
        ((float4*)d1)[q4] = make_float4(br[2*q4], bi[2*q4], br[2*q4+1], bi[2*q4+1]);
    }
}

// ---- kE: y[row][w] = (1/16384)*(Re(Z0) + 2*sum_{k=1..31} Re(Zk e^{i th})) + bias
__global__ __launch_bounds__(256) void kE(const float* __restrict__ Z,
                                          const float* __restrict__ bias,
                                          float* __restrict__ out) {
    __shared__ float tabs[258];
    __shared__ float zs[4][64];
    build_tab(tabs);
    int t = threadIdx.x;
    int wv = t >> 6, lane = t & 63;
    size_t row = (size_t)blockIdx.x * 4 + wv;  // (b,co,h) rows = 131072
    int co = ((int)(row >> 7)) & 63;
    zs[wv][lane] = Z[row * 64 + lane];
    __syncthreads();
    const float* cosT = tabs;
    const float* sinT = tabs + 129;
    float Se = 0.f, So = 0.f;
    int idx = lane;  // (k*lane) & 127, k starts at 1
    #pragma unroll
    for (int k = 1; k < 32; ++k) {
        float c = cosT[idx], s = sinT[idx];
        float zr_ = zs[wv][2 * k], zi_ = zs[wv][2 * k + 1];
        if (k & 1) { So = fmaf(zr_, c, So); So = fmaf(-zi_, s, So); }
        else       { Se = fmaf(zr_, c, Se); Se = fmaf(-zi_, s, Se); }
        idx = (idx + lane) & 127;
    }
    float dc = zs[wv][0];
    float bv = bias[co];
    const float inv = 6.103515625e-05f;  // 1/16384
    float y0 = fmaf(2.f * (Se + So), inv, dc * inv) + bv;  // w = lane
    float y1 = fmaf(2.f * (Se - So), inv, dc * inv) + bv;  // w = lane+64
    out[row * 128 + lane] = y0;
    out[row * 128 + 64 + lane] = y1;
}

extern "C" void kernel_launch(void* const* d_in, const int* in_sizes, int n_in,
                              void* d_out, int out_size, void* d_ws, size_t ws_size,
                              hipStream_t stream) {
    (void)in_sizes; (void)n_in; (void)out_size; (void)ws_size;
    const float* x    = (const float*)d_in[0];
    const float* wgt  = (const float*)d_in[1];
    const float* bias = (const float*)d_in[2];
    float* outp  = (float*)d_out;
    float* bufA  = (float*)d_ws;                            // 32 MiB
    float* bufXF = (float*)((char*)d_ws + 33554432);        // 16 MiB
    float* bufYF = (float*)((char*)d_ws + 50331648);        // 16 MiB
    float* bufZ  = bufA;                                    // reuse A
    hipLaunchKernelGGL(kA, dim3(2048), dim3(256), 0, stream, x, bufA);
    hipLaunchKernelGGL(kB, dim3(1024), dim3(256), 0, stream, bufA, bufXF);
    hipLaunchKernelGGL(kC, dim3(512), dim3(256), 0, stream, bufXF, wgt, bufYF);
    hipLaunchKernelGGL(kD, dim3(1024), dim3(256), 0, stream, bufYF, bufZ);
    hipLaunchKernelGGL(kE, dim3(32768), dim3(256), 0, stream, bufZ, bias, outp);
}

// Round 5
// 187.021 us; speedup vs baseline: 2.3765x; 1.2508x over previous
//
#include <hip/hip_runtime.h>

// FactorizedSpectralConv2d: B=16, CIN=COUT=64, H=W=128, MH=MW=32, super_res=1
// Pipeline: kA (W-rDFT keep 32, GEMM-style) -> kB (H-DFT at 64 retained ky) ->
// kC (per-mode channel mix) -> kD (inverse H-DFT) -> kE (inverse W-rDFT + bias,
// GEMM-style).

__device__ __forceinline__ void build_tab(float* tabs) {
    int t = threadIdx.x;
    if (t < 128) {
        float ang = (float)t * 0.049087385212340517f;  // 2*pi/128
        float s, c;
        sincosf(ang, &s, &c);
        tabs[t] = c;        // cos at [0..127]
        tabs[129 + t] = s;  // sin at [129..256]
    }
}

// ---- kA: A[row=(b,ci,h)][q=2kx+p] = rDFT_W(x)[kx], kx=0..31 ---------------
__global__ __launch_bounds__(256) void kA(const float* __restrict__ x,
                                          float* __restrict__ A) {
    __shared__ __align__(16) float xeo[64 * 132];   // 33.8 KB
    __shared__ __align__(16) float Twid[64 * 64];   // 16 KB
    int t = threadIdx.x;
    int bid = blockIdx.x;
    size_t bc = bid >> 1;
    int hbase = (bid & 1) << 6;
    #pragma unroll
    for (int i = 0; i < 16; ++i) {
        int e = t + i * 256;
        int w = e >> 6, q = e & 63, kx = q >> 1;
        int idx = (w * kx) & 127;
        float ang = (float)idx * 0.049087385212340517f;
        float s, c;
        sincosf(ang, &s, &c);
        Twid[e] = (q & 1) ? -s : c;
    }
    const float* xb = x + bc * 16384 + (size_t)hbase * 128;
    int w4 = (t & 15) * 4;
    #pragma unroll
    for (int it = 0; it < 4; ++it) {
        int h = it * 16 + (t >> 4);
        float4 lo = *(const float4*)(xb + h * 128 + w4);
        float4 hi = *(const float4*)(xb + h * 128 + w4 + 64);
        ((float2*)&xeo[(w4 + 0) * 132])[h] = make_float2(lo.x + hi.x, lo.x - hi.x);
        ((float2*)&xeo[(w4 + 1) * 132])[h] = make_float2(lo.y + hi.y, lo.y - hi.y);
        ((float2*)&xeo[(w4 + 2) * 132])[h] = make_float2(lo.z + hi.z, lo.z - hi.z);
        ((float2*)&xeo[(w4 + 3) * 132])[h] = make_float2(lo.w + hi.w, lo.w - hi.w);
    }
    __syncthreads();
    int l = t & 63, wv = t >> 6;
    int h0 = (l & 15) * 4;
    int q0 = wv * 16 + (l >> 4) * 4;
    float4 acc0 = {0,0,0,0}, acc1 = {0,0,0,0}, acc2 = {0,0,0,0}, acc3 = {0,0,0,0};
    const float4* xv = (const float4*)xeo;   // 33 float4 per w-row
    const float4* tv = (const float4*)Twid;  // 16 float4 per w-row
    int xoff = 2 * (l & 15);
    int toff = q0 >> 2;
    for (int w = 0; w < 64; ++w) {
        float4 d0 = xv[w * 33 + xoff];      // ve(h0),vo(h0),ve(h0+1),vo(h0+1)
        float4 d1 = xv[w * 33 + xoff + 1];  // h0+2, h0+3
        float4 tw = tv[w * 16 + toff];      // Tc(kxe),Ts(kxe),Tc(kxo),Ts(kxo)
        acc0.x = fmaf(d0.x, tw.x, acc0.x); acc0.y = fmaf(d0.x, tw.y, acc0.y);
        acc0.z = fmaf(d0.y, tw.z, acc0.z); acc0.w = fmaf(d0.y, tw.w, acc0.w);
        acc1.x = fmaf(d0.z, tw.x, acc1.x); acc1.y = fmaf(d0.z, tw.y, acc1.y);
        acc1.z = fmaf(d0.w, tw.z, acc1.z); acc1.w = fmaf(d0.w, tw.w, acc1.w);
        acc2.x = fmaf(d1.x, tw.x, acc2.x); acc2.y = fmaf(d1.x, tw.y, acc2.y);
        acc2.z = fmaf(d1.y, tw.z, acc2.z); acc2.w = fmaf(d1.y, tw.w, acc2.w);
        acc3.x = fmaf(d1.z, tw.x, acc3.x); acc3.y = fmaf(d1.z, tw.y, acc3.y);
        acc3.z = fmaf(d1.w, tw.z, acc3.z); acc3.w = fmaf(d1.w, tw.w, acc3.w);
    }
    float* Ab = A + (bc * 128 + hbase + h0) * 64 + q0;
    *(float4*)(Ab)       = acc0;
    *(float4*)(Ab + 64)  = acc1;
    *(float4*)(Ab + 128) = acc2;
    *(float4*)(Ab + 192) = acc3;
}

// ---- kB: XF[(b,ci)][j*32+kx] = sum_h A[h][kx]*e^{-2pi i ky(j) h/128} ------
__global__ __launch_bounds__(256) void kB(const float* __restrict__ A,
                                          float* __restrict__ XF) {
    __shared__ float tabs[258];
    __shared__ float At[128 * 64];  // [h][2*kx+p], 32 KB
    build_tab(tabs);
    int t = threadIdx.x;
    size_t bc = blockIdx.x;  // b*64+ci, 1024 blocks
    const float4* src = (const float4*)(A + bc * 8192);
    float4* d4 = (float4*)At;
    #pragma unroll
    for (int i = 0; i < 8; ++i) d4[t + i * 256] = src[t + i * 256];
    __syncthreads();
    int j = t & 63;
    int kx0 = (t >> 6) * 8;
    int ky = (j < 32) ? j : j + 64;
    const float* cosT = tabs;
    const float* sinT = tabs + 129;
    float re[8] = {0, 0, 0, 0, 0, 0, 0, 0};
    float im[8] = {0, 0, 0, 0, 0, 0, 0, 0};
    int idx = 0;  // (ky*h) & 127
    for (int h = 0; h < 128; ++h) {
        float c = cosT[idx], s = sinT[idx];
        const float4* ap = (const float4*)(&At[h * 64 + 2 * kx0]);
        #pragma unroll
        for (int q4 = 0; q4 < 4; ++q4) {
            float4 av = ap[q4];
            int q0 = 2 * q4, q1 = 2 * q4 + 1;
            re[q0] = fmaf(av.x, c, re[q0]); re[q0] = fmaf(av.y, s, re[q0]);
            im[q0] = fmaf(av.y, c, im[q0]); im[q0] = fmaf(-av.x, s, im[q0]);
            re[q1] = fmaf(av.z, c, re[q1]); re[q1] = fmaf(av.w, s, re[q1]);
            im[q1] = fmaf(av.w, c, im[q1]); im[q1] = fmaf(-av.z, s, im[q1]);
        }
        idx = (idx + ky) & 127;
    }
    float* dst = XF + bc * 4096 + (size_t)(j * 32 + kx0) * 2;
    #pragma unroll
    for (int q4 = 0; q4 < 4; ++q4) {
        ((float4*)dst)[q4] =
            make_float4(re[2 * q4], im[2 * q4], re[2 * q4 + 1], im[2 * q4 + 1]);
    }
}

// ---- kC: per-mode channel mix, coalesced-weight version. ------------------
__global__ __launch_bounds__(256) void kC(const float* __restrict__ XF,
                                          const float* __restrict__ Wgt,
                                          float* __restrict__ YF) {
    __shared__ float2 Xs[8 * 16 * 16];  // [ci_l][b][mx], 16 KB
    __shared__ float2 Ws[8 * 16 * 16];  // [ci_l][co_l][mx], 16 KB
    int t = threadIdx.x;
    int bid = blockIdx.x;
    int mxh = bid & 1;
    int cot = (bid >> 1) & 3;
    int my  = (bid >> 3) & 31;
    int c   = bid >> 8;
    int co0 = cot * 16;
    int slotbase = (c * 32 + my) * 32 + mxh * 16;  // + mx, in [0,2048)
    int mx = t & 15;
    int b  = t >> 4;
    float2 acc[16];
    #pragma unroll
    for (int i = 0; i < 16; ++i) acc[i] = make_float2(0.f, 0.f);
    const size_t wre_base = (size_t)c * 4096 * 1024 + (size_t)my * 32 + mxh * 16;
    const size_t wim_base = wre_base + (size_t)2 * 4096 * 1024;
    for (int cc = 0; cc < 8; ++cc) {
        __syncthreads();
        #pragma unroll
        for (int s = 0; s < 8; ++s) {
            int e = t + s * 256;
            int emx = e & 15, eb = (e >> 4) & 15, eci = e >> 8;
            int ci = cc * 8 + eci;
            Xs[e] = *(const float2*)(XF + ((size_t)(eb * 64 + ci) * 2048 + slotbase + emx) * 2);
        }
        #pragma unroll
        for (int s = 0; s < 8; ++s) {
            int e = t + s * 256;
            int emx = e & 15, eco = (e >> 4) & 15, eci = e >> 8;
            size_t g = (size_t)(cc * 8 + eci) * 64 + co0 + eco;
            float wr = Wgt[wre_base + g * 1024 + emx];
            float wi = Wgt[wim_base + g * 1024 + emx];
            Ws[e] = make_float2(wr, wi);
        }
        __syncthreads();
        #pragma unroll
        for (int ci_l = 0; ci_l < 8; ++ci_l) {
            float2 xv = Xs[(ci_l * 16 + b) * 16 + mx];
            #pragma unroll
            for (int co_l = 0; co_l < 16; ++co_l) {
                float2 w = Ws[(ci_l * 16 + co_l) * 16 + mx];
                acc[co_l].x = fmaf(xv.x, w.x, acc[co_l].x);
                acc[co_l].x = fmaf(-xv.y, w.y, acc[co_l].x);
                acc[co_l].y = fmaf(xv.x, w.y, acc[co_l].y);
                acc[co_l].y = fmaf(xv.y, w.x, acc[co_l].y);
            }
        }
    }
    #pragma unroll
    for (int co_l = 0; co_l < 16; ++co_l) {
        *(float2*)(YF + ((size_t)(b * 64 + co0 + co_l) * 2048 + slotbase + mx) * 2) = acc[co_l];
    }
}

// ---- kD: Z[(b,co)][h][kx] = sum_j YF[j][kx]*e^{+2pi i h ky(j)/128} --------
__global__ __launch_bounds__(256) void kD(const float* __restrict__ YF,
                                          float* __restrict__ Z) {
    __shared__ float tabs[258];
    __shared__ float Ys[4096];  // [j][kx][re,im], 16 KB
    build_tab(tabs);
    int t = threadIdx.x;
    size_t bo = blockIdx.x;  // b*64+co, 1024 blocks
    const float4* src = (const float4*)(YF + bo * 4096);
    #pragma unroll
    for (int i = 0; i < 4; ++i) ((float4*)Ys)[t + i * 256] = src[t + i * 256];
    __syncthreads();
    int hl = t & 63;
    int kx0 = (t >> 6) * 8;
    const float* cosT = tabs;
    const float* sinT = tabs + 129;
    float ar[8] = {0,0,0,0,0,0,0,0}, ai[8] = {0,0,0,0,0,0,0,0};
    float br[8] = {0,0,0,0,0,0,0,0}, bi[8] = {0,0,0,0,0,0,0,0};
    int idx = 0;
    for (int j = 0; j < 64; ++j) {
        int ky = (j < 32) ? j : j + 64;
        float cc = cosT[idx], ss = sinT[idx];
        float sg = (ky & 1) ? -1.f : 1.f;
        float c2 = sg * cc, s2 = sg * ss;
        const float4* yp = (const float4*)(&Ys[(j * 32 + kx0) * 2]);
        #pragma unroll
        for (int q4 = 0; q4 < 4; ++q4) {
            float4 v = yp[q4];
            int q0 = 2 * q4, q1 = 2 * q4 + 1;
            ar[q0] = fmaf(v.x, cc, ar[q0]); ar[q0] = fmaf(-v.y, ss, ar[q0]);
            ai[q0] = fmaf(v.x, ss, ai[q0]); ai[q0] = fmaf(v.y, cc, ai[q0]);
            br[q0] = fmaf(v.x, c2, br[q0]); br[q0] = fmaf(-v.y, s2, br[q0]);
            bi[q0] = fmaf(v.x, s2, bi[q0]); bi[q0] = fmaf(v.y, c2, bi[q0]);
            ar[q1] = fmaf(v.z, cc, ar[q1]); ar[q1] = fmaf(-v.w, ss, ar[q1]);
            ai[q1] = fmaf(v.z, ss, ai[q1]); ai[q1] = fmaf(v.w, cc, ai[q1]);
            br[q1] = fmaf(v.z, c2, br[q1]); br[q1] = fmaf(-v.w, s2, br[q1]);
            bi[q1] = fmaf(v.z, s2, bi[q1]); bi[q1] = fmaf(v.w, c2, bi[q1]);
        }
        idx = (idx + hl) & 127;
        if (j == 31) idx = (idx + ((hl & 1) << 6)) & 127;  // ky jumps 31->96
    }
    float* d0 = Z + (bo * 128 + hl) * 64 + kx0 * 2;
    float* d1 = Z + (bo * 128 + hl + 64) * 64 + kx0 * 2;
    #pragma unroll
    for (int q4 = 0; q4 < 4; ++q4) {
        ((float4*)d0)[q4] = make_float4(ar[2*q4], ai[2*q4], ar[2*q4+1], ai[2*q4+1]);
        ((float4*)d1)[q4] = make_float4(br[2*q4], bi[2*q4], br[2*q4+1], bi[2*q4+1]);
    }
}

// ---- kE (GEMM-style): Y[h][w] = sum_q Z[h][q]*T[q][w] + bias --------------
// T[0][w]=inv, T[1][w]=0 (DC imag dropped), T[2k][w]=2inv*cos(2pi k w/128),
// T[2k+1][w]=-2inv*sin(2pi k w/128). Block = (bo, h-half): 2048 blocks.
// Thread tile 8h x 4w: 32 fma / 3 ds_read_b128.
__global__ __launch_bounds__(256) void kE(const float* __restrict__ Z,
                                          const float* __restrict__ bias,
                                          float* __restrict__ out) {
    __shared__ float tabs[258];
    __shared__ __align__(16) float Ts[64 * 128];  // 32 KB
    __shared__ __align__(16) float Zt[64 * 68];   // 17 KB, [q][h] stride 68
    build_tab(tabs);
    __syncthreads();
    int t = threadIdx.x;
    int bid = blockIdx.x;
    size_t bo = bid >> 1;          // b*64+co
    int hbase = (bid & 1) << 6;
    const float inv = 6.103515625e-05f;  // 1/16384
    #pragma unroll
    for (int i = 0; i < 32; ++i) {
        int e = t + i * 256;
        int q = e >> 7, w = e & 127;
        int k = q >> 1;
        int idx = (k * w) & 127;
        float val;
        if (q == 0)      val = inv;
        else if (q == 1) val = 0.f;
        else if (q & 1)  val = -2.f * inv * tabs[129 + idx];
        else             val =  2.f * inv * tabs[idx];
        Ts[e] = val;
    }
    const float* Zb = Z + (bo * 128 + hbase) * 64;
    #pragma unroll
    for (int s = 0; s < 4; ++s) {
        int u = t + s * 256;          // 0..1023
        int h = u & 63, qg = u >> 6;  // qg 0..15
        float4 v = *(const float4*)(Zb + h * 64 + qg * 4);
        Zt[(qg * 4 + 0) * 68 + h] = v.x;
        Zt[(qg * 4 + 1) * 68 + h] = v.y;
        Zt[(qg * 4 + 2) * 68 + h] = v.z;
        Zt[(qg * 4 + 3) * 68 + h] = v.w;
    }
    __syncthreads();
    int w0 = (t & 31) * 4;
    int h0 = (t >> 5) * 8;
    float4 acc[8];
    #pragma unroll
    for (int j = 0; j < 8; ++j) acc[j] = make_float4(0.f, 0.f, 0.f, 0.f);
    #pragma unroll 2
    for (int q = 0; q < 64; ++q) {
        const float4* zp = (const float4*)(&Zt[q * 68 + h0]);
        float4 z0 = zp[0], z1 = zp[1];
        float4 tw = *(const float4*)(&Ts[q * 128 + w0]);
        acc[0].x = fmaf(z0.x, tw.x, acc[0].x); acc[0].y = fmaf(z0.x, tw.y, acc[0].y);
        acc[0].z = fmaf(z0.x, tw.z, acc[0].z); acc[0].w = fmaf(z0.x, tw.w, acc[0].w);
        acc[1].x = fmaf(z0.y, tw.x, acc[1].x); acc[1].y = fmaf(z0.y, tw.y, acc[1].y);
        acc[1].z = fmaf(z0.y, tw.z, acc[1].z); acc[1].w = fmaf(z0.y, tw.w, acc[1].w);
        acc[2].x = fmaf(z0.z, tw.x, acc[2].x); acc[2].y = fmaf(z0.z, tw.y, acc[2].y);
        acc[2].z = fmaf(z0.z, tw.z, acc[2].z); acc[2].w = fmaf(z0.z, tw.w, acc[2].w);
        acc[3].x = fmaf(z0.w, tw.x, acc[3].x); acc[3].y = fmaf(z0.w, tw.y, acc[3].y);
        acc[3].z = fmaf(z0.w, tw.z, acc[3].z); acc[3].w = fmaf(z0.w, tw.w, acc[3].w);
        acc[4].x = fmaf(z1.x, tw.x, acc[4].x); acc[4].y = fmaf(z1.x, tw.y, acc[4].y);
        acc[4].z = fmaf(z1.x, tw.z, acc[4].z); acc[4].w = fmaf(z1.x, tw.w, acc[4].w);
        acc[5].x = fmaf(z1.y, tw.x, acc[5].x); acc[5].y = fmaf(z1.y, tw.y, acc[5].y);
        acc[5].z = fmaf(z1.y, tw.z, acc[5].z); acc[5].w = fmaf(z1.y, tw.w, acc[5].w);
        acc[6].x = fmaf(z1.z, tw.x, acc[6].x); acc[6].y = fmaf(z1.z, tw.y, acc[6].y);
        acc[6].z = fmaf(z1.z, tw.z, acc[6].z); acc[6].w = fmaf(z1.z, tw.w, acc[6].w);
        acc[7].x = fmaf(z1.w, tw.x, acc[7].x); acc[7].y = fmaf(z1.w, tw.y, acc[7].y);
        acc[7].z = fmaf(z1.w, tw.z, acc[7].z); acc[7].w = fmaf(z1.w, tw.w, acc[7].w);
    }
    float bv = bias[(int)(bo & 63)];
    float* ob = out + ((size_t)(bo * 128 + hbase + h0)) * 128 + w0;
    #pragma unroll
    for (int j = 0; j < 8; ++j) {
        float4 r = acc[j];
        r.x += bv; r.y += bv; r.z += bv; r.w += bv;
        *(float4*)(ob + (size_t)j * 128) = r;
    }
}

extern "C" void kernel_launch(void* const* d_in, const int* in_sizes, int n_in,
                              void* d_out, int out_size, void* d_ws, size_t ws_size,
                              hipStream_t stream) {
    (void)in_sizes; (void)n_in; (void)out_size; (void)ws_size;
    const float* x    = (const float*)d_in[0];
    const float* wgt  = (const float*)d_in[1];
    const float* bias = (const float*)d_in[2];
    float* outp  = (float*)d_out;
    float* bufA  = (float*)d_ws;                            // 32 MiB
    float* bufXF = (float*)((char*)d_ws + 33554432);        // 16 MiB
    float* bufYF = (float*)((char*)d_ws + 50331648);        // 16 MiB
    float* bufZ  = bufA;                                    // reuse A
    hipLaunchKernelGGL(kA, dim3(2048), dim3(256), 0, stream, x, bufA);
    hipLaunchKernelGGL(kB, dim3(1024), dim3(256), 0, stream, bufA, bufXF);
    hipLaunchKernelGGL(kC, dim3(512), dim3(256), 0, stream, bufXF, wgt, bufYF);
    hipLaunchKernelGGL(kD, dim3(1024), dim3(256), 0, stream, bufYF, bufZ);
    hipLaunchKernelGGL(kE, dim3(2048), dim3(256), 0, stream, bufZ, bias, outp);
}

// Round 6
// 178.118 us; speedup vs baseline: 2.4953x; 1.0500x over previous
//
#include <hip/hip_runtime.h>

// FactorizedSpectralConv2d: B=16, CIN=COUT=64, H=W=128, MH=MW=32, super_res=1
// Pipeline: kA (W-rDFT keep 32, GEMM-style, phased K) -> kB (H-DFT at 64
// retained ky) -> kC (per-mode channel mix) -> kD (inverse H-DFT) ->
// kE (inverse W-rDFT + bias, GEMM-style).

__device__ __forceinline__ void build_tab(float* tabs) {
    int t = threadIdx.x;
    if (t < 128) {
        float ang = (float)t * 0.049087385212340517f;  // 2*pi/128
        float s, c;
        sincosf(ang, &s, &c);
        tabs[t] = c;        // cos at [0..127]
        tabs[129 + t] = s;  // sin at [129..256]
    }
}

// ---- kA: A[row=(b,ci,h)][q=2kx+p] = rDFT_W(x)[kx], kx=0..31 ---------------
// One block per (b,ci) image. M=128 h, N=64 q, K=64 w (folded), K phased by 16.
// xeo[w_l][(ve,vo) per h], row stride 260 floats (260%32=4 -> spread banks).
// Thread tile: 8h x 4q (h = 2*th + {0,1} + 32*i), 32 fma / 5 LDS instrs.
__global__ __launch_bounds__(256) void kA(const float* __restrict__ x,
                                          float* __restrict__ A) {
    __shared__ float tabs[258];
    __shared__ __align__(16) float Twid[64 * 64];   // [w][q], 16 KB
    __shared__ __align__(16) float xeo[16 * 260];   // 16.6 KB
    build_tab(tabs);
    __syncthreads();
    int t = threadIdx.x;
    size_t bc = blockIdx.x;  // b*64+ci, 1024 blocks
    // Twid from table: Twid[w][q] = (q&1) ? -sin(2pi*w*kx/128) : cos(...), kx=q>>1
    #pragma unroll
    for (int i = 0; i < 16; ++i) {
        int e = t + i * 256;
        int w = e >> 6, q = e & 63, kx = q >> 1;
        int idx = (w * kx) & 127;
        float cv = tabs[idx], sv = tabs[129 + idx];
        Twid[e] = (q & 1) ? -sv : cv;
    }
    const float* xb = x + bc * 16384;
    int th = t & 15;        // h-group
    int tq = t >> 4;        // q-group
    int q0 = tq * 4;
    int wl4 = (t & 3) * 4;  // staging: w_l 0,4,8,12
    int hb  = t >> 2;       // staging: h 0..63 (+64)
    // stage phase ph: w_l 0..15 <- global w = ph*16 + w_l, all 128 h
    auto stage = [&](int ph) {
        #pragma unroll
        for (int it = 0; it < 2; ++it) {
            int h = it * 64 + hb;
            float4 lo = *(const float4*)(xb + h * 128 + ph * 16 + wl4);
            float4 hi = *(const float4*)(xb + h * 128 + ph * 16 + wl4 + 64);
            *(float2*)(&xeo[(wl4 + 0) * 260 + 2 * h]) = make_float2(lo.x + hi.x, lo.x - hi.x);
            *(float2*)(&xeo[(wl4 + 1) * 260 + 2 * h]) = make_float2(lo.y + hi.y, lo.y - hi.y);
            *(float2*)(&xeo[(wl4 + 2) * 260 + 2 * h]) = make_float2(lo.z + hi.z, lo.z - hi.z);
            *(float2*)(&xeo[(wl4 + 3) * 260 + 2 * h]) = make_float2(lo.w + hi.w, lo.w - hi.w);
        }
    };
    stage(0);
    float4 acc8[8];
    #pragma unroll
    for (int j = 0; j < 8; ++j) acc8[j] = make_float4(0.f, 0.f, 0.f, 0.f);
    for (int ph = 0; ph < 4; ++ph) {
        __syncthreads();  // staging of ph visible
        #pragma unroll 4
        for (int wl = 0; wl < 16; ++wl) {
            int w = ph * 16 + wl;
            float4 tw = *(const float4*)(&Twid[w * 64 + q0]);  // broadcast x16
            const float* xr = &xeo[wl * 260 + 4 * th];
            #pragma unroll
            for (int i = 0; i < 4; ++i) {
                float4 d = *(const float4*)(xr + 64 * i);  // ve(hA),vo(hA),ve(hB),vo(hB)
                acc8[2*i].x   = fmaf(d.x, tw.x, acc8[2*i].x);
                acc8[2*i].y   = fmaf(d.x, tw.y, acc8[2*i].y);
                acc8[2*i].z   = fmaf(d.y, tw.z, acc8[2*i].z);
                acc8[2*i].w   = fmaf(d.y, tw.w, acc8[2*i].w);
                acc8[2*i+1].x = fmaf(d.z, tw.x, acc8[2*i+1].x);
                acc8[2*i+1].y = fmaf(d.z, tw.y, acc8[2*i+1].y);
                acc8[2*i+1].z = fmaf(d.w, tw.z, acc8[2*i+1].z);
                acc8[2*i+1].w = fmaf(d.w, tw.w, acc8[2*i+1].w);
            }
        }
        __syncthreads();  // compute done before restage
        if (ph < 3) stage(ph + 1);
    }
    #pragma unroll
    for (int i = 0; i < 4; ++i) {
        #pragma unroll
        for (int r = 0; r < 2; ++r) {
            int h = 32 * i + 2 * th + r;
            *(float4*)(A + (bc * 128 + h) * 64 + q0) = acc8[2*i + r];
        }
    }
}

// ---- kB: XF[(b,ci)][j*32+kx] = sum_h A[h][kx]*e^{-2pi i ky(j) h/128} ------
__global__ __launch_bounds__(256) void kB(const float* __restrict__ A,
                                          float* __restrict__ XF) {
    __shared__ float tabs[258];
    __shared__ float At[128 * 64];  // [h][2*kx+p], 32 KB
    build_tab(tabs);
    int t = threadIdx.x;
    size_t bc = blockIdx.x;  // b*64+ci, 1024 blocks
    const float4* src = (const float4*)(A + bc * 8192);
    float4* d4 = (float4*)At;
    #pragma unroll
    for (int i = 0; i < 8; ++i) d4[t + i * 256] = src[t + i * 256];
    __syncthreads();
    int j = t & 63;
    int kx0 = (t >> 6) * 8;
    int ky = (j < 32) ? j : j + 64;
    const float* cosT = tabs;
    const float* sinT = tabs + 129;
    float re[8] = {0, 0, 0, 0, 0, 0, 0, 0};
    float im[8] = {0, 0, 0, 0, 0, 0, 0, 0};
    int idx = 0;  // (ky*h) & 127
    for (int h = 0; h < 128; ++h) {
        float c = cosT[idx], s = sinT[idx];
        const float4* ap = (const float4*)(&At[h * 64 + 2 * kx0]);
        #pragma unroll
        for (int q4 = 0; q4 < 4; ++q4) {
            float4 av = ap[q4];
            int q0 = 2 * q4, q1 = 2 * q4 + 1;
            re[q0] = fmaf(av.x, c, re[q0]); re[q0] = fmaf(av.y, s, re[q0]);
            im[q0] = fmaf(av.y, c, im[q0]); im[q0] = fmaf(-av.x, s, im[q0]);
            re[q1] = fmaf(av.z, c, re[q1]); re[q1] = fmaf(av.w, s, re[q1]);
            im[q1] = fmaf(av.w, c, im[q1]); im[q1] = fmaf(-av.z, s, im[q1]);
        }
        idx = (idx + ky) & 127;
    }
    float* dst = XF + bc * 4096 + (size_t)(j * 32 + kx0) * 2;
    #pragma unroll
    for (int q4 = 0; q4 < 4; ++q4) {
        ((float4*)dst)[q4] =
            make_float4(re[2 * q4], im[2 * q4], re[2 * q4 + 1], im[2 * q4 + 1]);
    }
}

// ---- kC: per-mode channel mix, coalesced-weight version. ------------------
__global__ __launch_bounds__(256) void kC(const float* __restrict__ XF,
                                          const float* __restrict__ Wgt,
                                          float* __restrict__ YF) {
    __shared__ float2 Xs[8 * 16 * 16];  // [ci_l][b][mx], 16 KB
    __shared__ float2 Ws[8 * 16 * 16];  // [ci_l][co_l][mx], 16 KB
    int t = threadIdx.x;
    int bid = blockIdx.x;
    int mxh = bid & 1;
    int cot = (bid >> 1) & 3;
    int my  = (bid >> 3) & 31;
    int c   = bid >> 8;
    int co0 = cot * 16;
    int slotbase = (c * 32 + my) * 32 + mxh * 16;  // + mx, in [0,2048)
    int mx = t & 15;
    int b  = t >> 4;
    float2 acc[16];
    #pragma unroll
    for (int i = 0; i < 16; ++i) acc[i] = make_float2(0.f, 0.f);
    const size_t wre_base = (size_t)c * 4096 * 1024 + (size_t)my * 32 + mxh * 16;
    const size_t wim_base = wre_base + (size_t)2 * 4096 * 1024;
    for (int cc = 0; cc < 8; ++cc) {
        __syncthreads();
        #pragma unroll
        for (int s = 0; s < 8; ++s) {
            int e = t + s * 256;
            int emx = e & 15, eb = (e >> 4) & 15, eci = e >> 8;
            int ci = cc * 8 + eci;
            Xs[e] = *(const float2*)(XF + ((size_t)(eb * 64 + ci) * 2048 + slotbase + emx) * 2);
        }
        #pragma unroll
        for (int s = 0; s < 8; ++s) {
            int e = t + s * 256;
            int emx = e & 15, eco = (e >> 4) & 15, eci = e >> 8;
            size_t g = (size_t)(cc * 8 + eci) * 64 + co0 + eco;
            float wr = Wgt[wre_base + g * 1024 + emx];
            float wi = Wgt[wim_base + g * 1024 + emx];
            Ws[e] = make_float2(wr, wi);
        }
        __syncthreads();
        #pragma unroll
        for (int ci_l = 0; ci_l < 8; ++ci_l) {
            float2 xv = Xs[(ci_l * 16 + b) * 16 + mx];
            #pragma unroll
            for (int co_l = 0; co_l < 16; ++co_l) {
                float2 w = Ws[(ci_l * 16 + co_l) * 16 + mx];
                acc[co_l].x = fmaf(xv.x, w.x, acc[co_l].x);
                acc[co_l].x = fmaf(-xv.y, w.y, acc[co_l].x);
                acc[co_l].y = fmaf(xv.x, w.y, acc[co_l].y);
                acc[co_l].y = fmaf(xv.y, w.x, acc[co_l].y);
            }
        }
    }
    #pragma unroll
    for (int co_l = 0; co_l < 16; ++co_l) {
        *(float2*)(YF + ((size_t)(b * 64 + co0 + co_l) * 2048 + slotbase + mx) * 2) = acc[co_l];
    }
}

// ---- kD: Z[(b,co)][h][kx] = sum_j YF[j][kx]*e^{+2pi i h ky(j)/128} --------
__global__ __launch_bounds__(256) void kD(const float* __restrict__ YF,
                                          float* __restrict__ Z) {
    __shared__ float tabs[258];
    __shared__ float Ys[4096];  // [j][kx][re,im], 16 KB
    build_tab(tabs);
    int t = threadIdx.x;
    size_t bo = blockIdx.x;  // b*64+co, 1024 blocks
    const float4* src = (const float4*)(YF + bo * 4096);
    #pragma unroll
    for (int i = 0; i < 4; ++i) ((float4*)Ys)[t + i * 256] = src[t + i * 256];
    __syncthreads();
    int hl = t & 63;
    int kx0 = (t >> 6) * 8;
    const float* cosT = tabs;
    const float* sinT = tabs + 129;
    float ar[8] = {0,0,0,0,0,0,0,0}, ai[8] = {0,0,0,0,0,0,0,0};
    float br[8] = {0,0,0,0,0,0,0,0}, bi[8] = {0,0,0,0,0,0,0,0};
    int idx = 0;
    for (int j = 0; j < 64; ++j) {
        int ky = (j < 32) ? j : j + 64;
        float cc = cosT[idx], ss = sinT[idx];
        float sg = (ky & 1) ? -1.f : 1.f;
        float c2 = sg * cc, s2 = sg * ss;
        const float4* yp = (const float4*)(&Ys[(j * 32 + kx0) * 2]);
        #pragma unroll
        for (int q4 = 0; q4 < 4; ++q4) {
            float4 v = yp[q4];
            int q0 = 2 * q4, q1 = 2 * q4 + 1;
            ar[q0] = fmaf(v.x, cc, ar[q0]); ar[q0] = fmaf(-v.y, ss, ar[q0]);
            ai[q0] = fmaf(v.x, ss, ai[q0]); ai[q0] = fmaf(v.y, cc, ai[q0]);
            br[q0] = fmaf(v.x, c2, br[q0]); br[q0] = fmaf(-v.y, s2, br[q0]);
            bi[q0] = fmaf(v.x, s2, bi[q0]); bi[q0] = fmaf(v.y, c2, bi[q0]);
            ar[q1] = fmaf(v.z, cc, ar[q1]); ar[q1] = fmaf(-v.w, ss, ar[q1]);
            ai[q1] = fmaf(v.z, ss, ai[q1]); ai[q1] = fmaf(v.w, cc, ai[q1]);
            br[q1] = fmaf(v.z, c2, br[q1]); br[q1] = fmaf(-v.w, s2, br[q1]);
            bi[q1] = fmaf(v.z, s2, bi[q1]); bi[q1] = fmaf(v.w, c2, bi[q1]);
        }
        idx = (idx + hl) & 127;
        if (j == 31) idx = (idx + ((hl & 1) << 6)) & 127;  // ky jumps 31->96
    }
    float* d0 = Z + (bo * 128 + hl) * 64 + kx0 * 2;
    float* d1 = Z + (bo * 128 + hl + 64) * 64 + kx0 * 2;
    #pragma unroll
    for (int q4 = 0; q4 < 4; ++q4) {
        ((float4*)d0)[q4] = make_float4(ar[2*q4], ai[2*q4], ar[2*q4+1], ai[2*q4+1]);
        ((float4*)d1)[q4] = make_float4(br[2*q4], bi[2*q4], br[2*q4+1], bi[2*q4+1]);
    }
}

// ---- kE (GEMM-style): Y[h][w] = sum_q Z[h][q]*T[q][w] + bias --------------
__global__ __launch_bounds__(256) void kE(const float* __restrict__ Z,
                                          const float* __restrict__ bias,
                                          float* __restrict__ out) {
    __shared__ float tabs[258];
    __shared__ __align__(16) float Ts[64 * 128];  // 32 KB
    __shared__ __align__(16) float Zt[64 * 68];   // 17 KB, [q][h] stride 68
    build_tab(tabs);
    __syncthreads();
    int t = threadIdx.x;
    int bid = blockIdx.x;
    size_t bo = bid >> 1;          // b*64+co
    int hbase = (bid & 1) << 6;
    const float inv = 6.103515625e-05f;  // 1/16384
    #pragma unroll
    for (int i = 0; i < 32; ++i) {
        int e = t + i * 256;
        int q = e >> 7, w = e & 127;
        int k = q >> 1;
        int idx = (k * w) & 127;
        float val;
        if (q == 0)      val = inv;
        else if (q == 1) val = 0.f;
        else if (q & 1)  val = -2.f * inv * tabs[129 + idx];
        else             val =  2.f * inv * tabs[idx];
        Ts[e] = val;
    }
    const float* Zb = Z + (bo * 128 + hbase) * 64;
    #pragma unroll
    for (int s = 0; s < 4; ++s) {
        int u = t + s * 256;          // 0..1023
        int h = u & 63, qg = u >> 6;  // qg 0..15
        float4 v = *(const float4*)(Zb + h * 64 + qg * 4);
        Zt[(qg * 4 + 0) * 68 + h] = v.x;
        Zt[(qg * 4 + 1) * 68 + h] = v.y;
        Zt[(qg * 4 + 2) * 68 + h] = v.z;
        Zt[(qg * 4 + 3) * 68 + h] = v.w;
    }
    __syncthreads();
    int w0 = (t & 31) * 4;
    int h0 = (t >> 5) * 8;
    float4 acc[8];
    #pragma unroll
    for (int j = 0; j < 8; ++j) acc[j] = make_float4(0.f, 0.f, 0.f, 0.f);
    #pragma unroll 2
    for (int q = 0; q < 64; ++q) {
        const float4* zp = (const float4*)(&Zt[q * 68 + h0]);
        float4 z0 = zp[0], z1 = zp[1];
        float4 tw = *(const float4*)(&Ts[q * 128 + w0]);
        acc[0].x = fmaf(z0.x, tw.x, acc[0].x); acc[0].y = fmaf(z0.x, tw.y, acc[0].y);
        acc[0].z = fmaf(z0.x, tw.z, acc[0].z); acc[0].w = fmaf(z0.x, tw.w, acc[0].w);
        acc[1].x = fmaf(z0.y, tw.x, acc[1].x); acc[1].y = fmaf(z0.y, tw.y, acc[1].y);
        acc[1].z = fmaf(z0.y, tw.z, acc[1].z); acc[1].w = fmaf(z0.y, tw.w, acc[1].w);
        acc[2].x = fmaf(z0.z, tw.x, acc[2].x); acc[2].y = fmaf(z0.z, tw.y, acc[2].y);
        acc[2].z = fmaf(z0.z, tw.z, acc[2].z); acc[2].w = fmaf(z0.z, tw.w, acc[2].w);
        acc[3].x = fmaf(z0.w, tw.x, acc[3].x); acc[3].y = fmaf(z0.w, tw.y, acc[3].y);
        acc[3].z = fmaf(z0.w, tw.z, acc[3].z); acc[3].w = fmaf(z0.w, tw.w, acc[3].w);
        acc[4].x = fmaf(z1.x, tw.x, acc[4].x); acc[4].y = fmaf(z1.x, tw.y, acc[4].y);
        acc[4].z = fmaf(z1.x, tw.z, acc[4].z); acc[4].w = fmaf(z1.x, tw.w, acc[4].w);
        acc[5].x = fmaf(z1.y, tw.x, acc[5].x); acc[5].y = fmaf(z1.y, tw.y, acc[5].y);
        acc[5].z = fmaf(z1.y, tw.z, acc[5].z); acc[5].w = fmaf(z1.y, tw.w, acc[5].w);
        acc[6].x = fmaf(z1.z, tw.x, acc[6].x); acc[6].y = fmaf(z1.z, tw.y, acc[6].y);
        acc[6].z = fmaf(z1.z, tw.z, acc[6].z); acc[6].w = fmaf(z1.z, tw.w, acc[6].w);
        acc[7].x = fmaf(z1.w, tw.x, acc[7].x); acc[7].y = fmaf(z1.w, tw.y, acc[7].y);
        acc[7].z = fmaf(z1.w, tw.z, acc[7].z); acc[7].w = fmaf(z1.w, tw.w, acc[7].w);
    }
    float bv = bias[(int)(bo & 63)];
    float* ob = out + ((size_t)(bo * 128 + hbase + h0)) * 128 + w0;
    #pragma unroll
    for (int j = 0; j < 8; ++j) {
        float4 r = acc[j];
        r.x += bv; r.y += bv; r.z += bv; r.w += bv;
        *(float4*)(ob + (size_t)j * 128) = r;
    }
}

extern "C" void kernel_launch(void* const* d_in, const int* in_sizes, int n_in,
                              void* d_out, int out_size, void* d_ws, size_t ws_size,
                              hipStream_t stream) {
    (void)in_sizes; (void)n_in; (void)out_size; (void)ws_size;
    const float* x    = (const float*)d_in[0];
    const float* wgt  = (const float*)d_in[1];
    const float* bias = (const float*)d_in[2];
    float* outp  = (float*)d_out;
    float* bufA  = (float*)d_ws;                            // 32 MiB
    float* bufXF = (float*)((char*)d_ws + 33554432);        // 16 MiB
    float* bufYF = (float*)((char*)d_ws + 50331648);        // 16 MiB
    float* bufZ  = bufA;                                    // reuse A
    hipLaunchKernelGGL(kA, dim3(1024), dim3(256), 0, stream, x, bufA);
    hipLaunchKernelGGL(kB, dim3(1024), dim3(256), 0, stream, bufA, bufXF);
    hipLaunchKernelGGL(kC, dim3(512), dim3(256), 0, stream, bufXF, wgt, bufYF);
    hipLaunchKernelGGL(kD, dim3(1024), dim3(256), 0, stream, bufYF, bufZ);
    hipLaunchKernelGGL(kE, dim3(2048), dim3(256), 0, stream, bufZ, bias, outp);
}